// Round 12
// baseline (71.939 us; speedup 1.0000x reference)
//
#include <hip/hip_runtime.h>
#include <hip/hip_bf16.h>

#define BC 4
#define NQ 1200
#define DIM 256
#define NH 8
#define HD 32
#define E3 768
#define MROWS (BC*NQ)
#define SCALE 0.17677669529663687f
#define L2E 1.4426950408889634f
#define SL2E (SCALE * L2E)

// VT2 global layout: [b][h][hh(2)][chunk(160)][d16(16)][8 keys]
#define VT2_PER_BH 40960
#define VT2_PER_HH 20480

typedef __attribute__((ext_vector_type(8))) short bf16x8;
typedef __attribute__((ext_vector_type(4))) float f32x4;
typedef __attribute__((ext_vector_type(2))) unsigned u32x2;
typedef __attribute__((ext_vector_type(4))) unsigned u32x4;

#if __has_builtin(__builtin_amdgcn_permlane32_swap) && __has_builtin(__builtin_amdgcn_permlane16_swap)
#define HAVE_PERMLANE 1
#else
#define HAVE_PERMLANE 0
#endif

__device__ inline short f2bf(float f) {
    __hip_bfloat16 h = __float2bfloat16(f);
    return *reinterpret_cast<short*>(&h);
}
// HW packed f32->bf16 (RNE), 1 instr for 2 values (T12 recipe)
__device__ __forceinline__ unsigned cvtpk(float lo, float hi) {
    unsigned r;
    asm("v_cvt_pk_bf16_f32 %0, %1, %2" : "=v"(r) : "v"(lo), "v"(hi));
    return r;
}

// async global->LDS, 16B per lane; LDS dest = wave-uniform base + lane*16
__device__ __forceinline__ void gll16(const void* g, void* l) {
    __builtin_amdgcn_global_load_lds(
        (const __attribute__((address_space(1))) unsigned*)g,
        (__attribute__((address_space(3))) unsigned*)l, 16, 0, 0);
}

// ---------------- beta (f32 exact) + center packing ----------------
__global__ void beta_ctr_kernel(const float* __restrict__ feat, const float* __restrict__ bw,
                                const float* __restrict__ bb, const float* __restrict__ bbox,
                                float* __restrict__ beta, float* __restrict__ ctr) {
    int gw = (blockIdx.x * 256 + threadIdx.x) >> 6;   // one wave per (b,n)
    int lane = threadIdx.x & 63;
    if (gw >= MROWS) return;
    const float* frow = feat + (size_t)gw * DIM;
    float acc[NH];
#pragma unroll
    for (int h = 0; h < NH; ++h) acc[h] = 0.f;
#pragma unroll
    for (int it = 0; it < DIM / 64; ++it) {
        int d = it * 64 + lane;
        float f = frow[d];
#pragma unroll
        for (int h = 0; h < NH; ++h) acc[h] += f * bw[h * DIM + d];
    }
#pragma unroll
    for (int h = 0; h < NH; ++h) {
#pragma unroll
        for (int off = 32; off; off >>= 1) acc[h] += __shfl_xor(acc[h], off);
    }
    int b = gw / NQ, n = gw % NQ;
#pragma unroll
    for (int h = 0; h < NH; ++h) {
        float v = acc[h] + bb[h];
        if (lane == h) beta[(b * NH + h) * NQ + n] = v;
    }
    if (lane == 0) {
        ctr[gw * 2]     = bbox[(size_t)gw * 10];
        ctr[gw * 2 + 1] = bbox[(size_t)gw * 10 + 1];
    }
}

// ---------------- GEMM: C[M,E] = A[M,256] * W[E,256]^T + bias ----------------
template<bool AF32, bool BF32, bool OUTF32, bool VTOUT, bool QSCALE>
__global__ __launch_bounds__(256) void gemm_k256(const void* __restrict__ Av,
                                                 const void* __restrict__ Bv,
                                                 const float* __restrict__ bias,
                                                 void* __restrict__ Cout, int Edim,
                                                 short* __restrict__ vtout) {
    __shared__ short as[64][40];
    __shared__ short bs[64][40];
    int m0 = blockIdx.y * 64, e0 = blockIdx.x * 64;
    int t = threadIdx.x, lane = t & 63, wid = t >> 6;
    int wr = (wid >> 1) * 32, wc = (wid & 1) * 32;
    f32x4 acc[2][2] = {};
    int lrow = t >> 2, lch = t & 3;
    const float qs = (QSCALE && e0 < DIM) ? SL2E : 1.f;

    for (int ks = 0; ks < DIM / 32; ++ks) {
        bf16x8 av, wv;
        if (AF32) {
            const float* A = (const float*)Av;
            float4 f0 = *(const float4*)(A + (size_t)(m0 + lrow) * DIM + ks * 32 + lch * 8);
            float4 f1 = *(const float4*)(A + (size_t)(m0 + lrow) * DIM + ks * 32 + lch * 8 + 4);
            u32x4 p = {cvtpk(f0.x, f0.y), cvtpk(f0.z, f0.w),
                       cvtpk(f1.x, f1.y), cvtpk(f1.z, f1.w)};
            av = __builtin_bit_cast(bf16x8, p);
        } else {
            av = *(const bf16x8*)((const short*)Av + (size_t)(m0 + lrow) * DIM + ks * 32 + lch * 8);
        }
        if (BF32) {
            const float* B = (const float*)Bv;
            float4 f0 = *(const float4*)(B + (size_t)(e0 + lrow) * DIM + ks * 32 + lch * 8);
            float4 f1 = *(const float4*)(B + (size_t)(e0 + lrow) * DIM + ks * 32 + lch * 8 + 4);
            u32x4 p = {cvtpk(f0.x * qs, f0.y * qs), cvtpk(f0.z * qs, f0.w * qs),
                       cvtpk(f1.x * qs, f1.y * qs), cvtpk(f1.z * qs, f1.w * qs)};
            wv = __builtin_bit_cast(bf16x8, p);
        } else {
            wv = *(const bf16x8*)((const short*)Bv + (size_t)(e0 + lrow) * DIM + ks * 32 + lch * 8);
        }
        __syncthreads();
        *(bf16x8*)&as[lrow][lch * 8] = av;
        *(bf16x8*)&bs[lrow][lch * 8] = wv;
        __syncthreads();
#pragma unroll
        for (int sm = 0; sm < 2; ++sm) {
            bf16x8 af = *(const bf16x8*)&as[wr + sm * 16 + (lane & 15)][(lane >> 4) * 8];
#pragma unroll
            for (int sn = 0; sn < 2; ++sn) {
                bf16x8 bfv = *(const bf16x8*)&bs[wc + sn * 16 + (lane & 15)][(lane >> 4) * 8];
                acc[sm][sn] = __builtin_amdgcn_mfma_f32_16x16x32_bf16(af, bfv, acc[sm][sn], 0, 0, 0);
            }
        }
    }
#pragma unroll
    for (int sm = 0; sm < 2; ++sm)
#pragma unroll
        for (int sn = 0; sn < 2; ++sn) {
            int e = e0 + wc + sn * 16 + (lane & 15);
            float bv = bias[e];
            if (QSCALE && e < DIM) bv *= SL2E;
            float vals[4];
            int mbase = m0 + wr + sm * 16 + (lane >> 4) * 4;
#pragma unroll
            for (int r = 0; r < 4; ++r) vals[r] = acc[sm][sn][r] + bv;
            if (VTOUT && e >= 2 * DIM) {
                int dv = e - 2 * DIM;
                int hv = dv >> 5, dd = dv & 31;
                int hh = dd >> 4, di = dd & 15;
                int bb = mbase / NQ, nn = mbase - bb * NQ;   // 4-key group never crosses b
                u32x2 o = {cvtpk(vals[0], vals[1]), cvtpk(vals[2], vals[3])};
                size_t off = (size_t)(bb * NH + hv) * VT2_PER_BH + hh * VT2_PER_HH
                           + (nn >> 3) * 128 + di * 8 + (nn & 7);
                *(u32x2*)&vtout[off] = o;
            } else {
#pragma unroll
                for (int r = 0; r < 4; ++r) {
                    int m = mbase + r;
                    if (OUTF32) ((float*)Cout)[(size_t)m * Edim + e] = vals[r];
                    else        ((short*)Cout)[(size_t)m * Edim + e] = f2bf(vals[r]);
                }
            }
        }
}

// ---------------- fused flash attention ----------------
// grid: (38, B*H); block 256 = 4 waves = 2 qgroup x 2 ksplit; wave-tile 16q x 64k.
// K/V via gll16 double-buffered LDS (32KB exactly -> 5 blocks/CU), centers from
// global (L2), P redistributed IN-REGISTER via permlane32/16_swap builtins.
#define KT_OFF 0
#define VT_OFF 8192
#define BUFSZ 16384
#if HAVE_PERMLANE
#define SMEM_SZ (2*BUFSZ)
#else
#define PL_OFF (2*BUFSZ)
#define SMEM_SZ (2*BUFSZ + 4096)
#endif
__global__ __launch_bounds__(256, 5) void attn_kernel(const short* __restrict__ qkv,
                                                      const short* __restrict__ vt2,
                                                      const float* __restrict__ beta,
                                                      const float* __restrict__ ctr,
                                                      short* __restrict__ attnb) {
    __shared__ __align__(16) char smem[SMEM_SZ];

    const int t = threadIdx.x, lane = t & 63, w = t >> 6;
    const int g = lane >> 4, i = lane & 15;
    const int qg = w >> 1, ksp = w & 1;
    const int bh = blockIdx.y, b = bh >> 3, h = bh & 7;
    const int q0 = blockIdx.x * 32 + qg * 16;
    const int q = q0 + i, qc = min(q, NQ - 1);
    const int kwb = ksp * 64;
    const int bq = b * NQ;

    bf16x8 qf = *(const bf16x8*)(qkv + (size_t)(bq + qc) * E3 + h * HD + g * 8);  // pre-scaled
    const float cqx = ctr[(bq + qc) * 2];
    const float cqy = ctr[(bq + qc) * 2 + 1];
    const float nbql = -beta[(b * NH + h) * NQ + qc] * L2E;

    const short onebf = (short)0x3F80;
    const bf16x8 ones = {onebf, onebf, onebf, onebf, onebf, onebf, onebf, onebf};

    float mcur = 0.f;
    f32x4 o0 = {}, o1 = {}, oS = {};              // oS: lsum via ones-row MFMA

    // staging source pointers (advance per tile; OOB lands in owned ws, masked)
    const int koff = ((t >> 6) << 4) + (t & 15);
    const short* kld0 = qkv + (size_t)bq * E3 + DIM + h * HD + (size_t)koff * E3 + ((t >> 4) & 3) * 8;
    const short* kld1 = kld0 + (size_t)64 * E3;
    const short* vld0 = vt2 + (size_t)bh * VT2_PER_BH + (((t >> 4) & 15)) * 128 + (t & 15) * 8;
    const short* vld1 = vld0 + VT2_PER_HH;
    const float* cgb = ctr + (size_t)bq * 2;

    auto stage_issue = [&](int base) {
        gll16(kld0, &smem[base + KT_OFF + t * 16]);
        gll16(kld1, &smem[base + KT_OFF + (t + 256) * 16]);
        gll16(vld0, &smem[base + VT_OFF + t * 16]);
        gll16(vld1, &smem[base + VT_OFF + (t + 256) * 16]);
        kld0 += (size_t)128 * E3; kld1 += (size_t)128 * E3;
        vld0 += 2048; vld1 += 2048;
    };

    stage_issue(0);
    __syncthreads();              // implicit vmcnt(0): tile 0 resident
    int cur = 0;

    for (int kb = 0; kb < NQ; kb += 128) {
        const bool haveNext = (kb + 128 < NQ);
        const bool tail = (kb + 128 > NQ);
        if (haveNext) stage_issue((cur ^ 1) * BUFSZ);   // async; completes by next barrier

        const int cb = cur * BUFSZ;
        float st[16];
        f32x4 cinit = {-mcur, -mcur, -mcur, -mcur};     // bake -m into MFMA C
#pragma unroll
        for (int kcl = 0; kcl < 4; ++kcl) {
            bf16x8 af = *(const bf16x8*)&smem[cb + KT_OFF + (((ksp * 4 + kcl) * 64 + lane) << 4)];
            f32x4 s = __builtin_amdgcn_mfma_f32_16x16x32_bf16(af, qf, cinit, 0, 0, 0);
            int kidx = kb + kwb + kcl * 16 + 4 * g;
            float4 cA = *(const float4*)(cgb + (size_t)kidx * 2);      // centers via L2
            float4 cB = *(const float4*)(cgb + (size_t)kidx * 2 + 4);
            float cxv[4] = {cA.x, cA.z, cB.x, cB.z};
            float cyv[4] = {cA.y, cA.w, cB.y, cB.w};
#pragma unroll
            for (int r = 0; r < 4; ++r) {
                float dx = cqx - cxv[r], dy = cqy - cyv[r];
                float d2 = __builtin_fmaf(dx, dx, dy * dy);
                float dist = __builtin_amdgcn_sqrtf(d2);
                st[kcl * 4 + r] = __builtin_fmaf(dist, nbql, s[r]);
            }
            if (tail) {
#pragma unroll
                for (int r = 0; r < 4; ++r)
                    if (kidx + r >= NQ) st[kcl * 4 + r] = -1e30f;
            }
        }

        // ---- local max only (no shuffles); rescale branch is rare & wave-uniform ----
        float a0 = fmaxf(fmaxf(st[0],  st[1]),  st[2]);
        float a1 = fmaxf(fmaxf(st[3],  st[4]),  st[5]);
        float a2 = fmaxf(fmaxf(st[6],  st[7]),  st[8]);
        float a3 = fmaxf(fmaxf(st[9],  st[10]), st[11]);
        float a4 = fmaxf(fmaxf(st[12], st[13]), st[14]);
        float vm = fmaxf(fmaxf(fmaxf(a0, a1), a2), fmaxf(fmaxf(a3, a4), st[15]));
        if (!__all(vm <= 8.0f)) {
            float vr = fmaxf(vm, __shfl_xor(vm, 16));   // row max (only when needed)
            vr = fmaxf(vr, __shfl_xor(vr, 32));
            float dm = fmaxf(vr, 0.f);
            float al = __builtin_amdgcn_exp2f(-dm);
            mcur += dm;
#pragma unroll
            for (int r = 0; r < 4; ++r) { o0[r] *= al; o1[r] *= al; }
            oS[0] *= al;                                 // only oS[0] is ever read
#pragma unroll
            for (int x = 0; x < 16; ++x) st[x] -= dm;
        }
#pragma unroll
        for (int x = 0; x < 16; ++x) st[x] = __builtin_amdgcn_exp2f(st[x]);

        // ---- P -> bf16 words ----
        unsigned pk0[4], pk1[4];
#pragma unroll
        for (int kcl = 0; kcl < 4; ++kcl) {
            pk0[kcl] = cvtpk(st[kcl * 4 + 0], st[kcl * 4 + 1]);
            pk1[kcl] = cvtpk(st[kcl * 4 + 2], st[kcl * 4 + 3]);
        }

        // ---- PV per 32-key chunk ----
#pragma unroll
        for (int kc2 = 0; kc2 < 2; ++kc2) {
            bf16x8 pbf;
#if HAVE_PERMLANE
            // in-register B-frag build:
            // (A0,A1)=pl32(P0,P2); (W0,W2)=pl16(A0,A1); (C0,C1)=pl32(P1,P3); (W1,W3)=pl16(C0,C1)
            u32x2 aa = __builtin_amdgcn_permlane32_swap(pk0[2 * kc2], pk0[2 * kc2 + 1], false, false);
            u32x2 bbp = __builtin_amdgcn_permlane16_swap(aa[0], aa[1], false, false);
            u32x2 cc = __builtin_amdgcn_permlane32_swap(pk1[2 * kc2], pk1[2 * kc2 + 1], false, false);
            u32x2 ddp = __builtin_amdgcn_permlane16_swap(cc[0], cc[1], false, false);
            u32x4 pv = {bbp[0], ddp[0], bbp[1], ddp[1]};
            pbf = __builtin_bit_cast(bf16x8, pv);
#else
#pragma unroll
            for (int kk = 0; kk < 2; ++kk) {
                int kcl = 2 * kc2 + kk;
                u32x2 pw = {pk0[kcl], pk1[kcl]};
                *(u32x2*)&smem[PL_OFF + (w << 10) + (((kk << 1) + (g >> 1)) << 8) + (i << 4) + ((g & 1) << 3)] = pw;
            }
            pbf = *(const bf16x8*)&smem[PL_OFF + (w << 10) + (g << 8) + (i << 4)];
#endif
            int vidx = (8 * ksp + 4 * kc2 + g) * 16 + i;
            bf16x8 vf0 = *(const bf16x8*)&smem[cb + VT_OFF + (vidx << 4)];
            bf16x8 vf1 = *(const bf16x8*)&smem[cb + VT_OFF + ((256 + vidx) << 4)];
            __builtin_amdgcn_s_setprio(1);
            o0 = __builtin_amdgcn_mfma_f32_16x16x32_bf16(vf0, pbf, o0, 0, 0, 0);
            o1 = __builtin_amdgcn_mfma_f32_16x16x32_bf16(vf1, pbf, o1, 0, 0, 0);
            oS = __builtin_amdgcn_mfma_f32_16x16x32_bf16(ones, pbf, oS, 0, 0, 0);  // lsum row
            __builtin_amdgcn_s_setprio(0);
        }

        __syncthreads();          // drains gll (vmcnt 0) + publishes buf^1
        cur ^= 1;
    }

    // ---- merge the two key-splits per q-group (oS[0] already row-reduced) ----
    float lsum = oS[0];
    float* mrg = (float*)smem;                 // [4][64][10]
    float* my = mrg + (w * 64 + lane) * 10;
    my[0] = mcur; my[1] = lsum;
#pragma unroll
    for (int r = 0; r < 4; ++r) { my[2 + r] = o0[r]; my[6 + r] = o1[r]; }
    __syncthreads();
    const float* pr = mrg + ((w ^ 1) * 64 + lane) * 10;
    float m2 = pr[0], l2 = pr[1];
    float mN = fmaxf(mcur, m2);
    float a1 = __builtin_amdgcn_exp2f(mcur - mN);
    float a2 = __builtin_amdgcn_exp2f(m2 - mN);
    float inv = 1.f / (lsum * a1 + l2 * a2);
    int hh = w & 1;                            // this wave writes d-half hh
    f32x4 mine = hh ? o1 : o0;
    if (q < NQ) {
        float vals[4];
#pragma unroll
        for (int r = 0; r < 4; ++r) vals[r] = (mine[r] * a1 + pr[2 + hh * 4 + r] * a2) * inv;
        u32x2 outv = {cvtpk(vals[0], vals[1]), cvtpk(vals[2], vals[3])};
        *(u32x2*)&attnb[(size_t)(bq + q) * DIM + h * HD + hh * 16 + 4 * g] = outv;
    }
}

extern "C" void kernel_launch(void* const* d_in, const int* in_sizes, int n_in,
                              void* d_out, int out_size, void* d_ws, size_t ws_size,
                              hipStream_t stream) {
    const float* bbox  = (const float*)d_in[0];
    const float* feat  = (const float*)d_in[1];
    const float* bw    = (const float*)d_in[2];
    const float* bb    = (const float*)d_in[3];
    const float* in_w  = (const float*)d_in[4];
    const float* in_b  = (const float*)d_in[5];
    const float* out_w = (const float*)d_in[6];
    const float* out_b = (const float*)d_in[7];
    float* out = (float*)d_out;

    char* ws = (char*)d_ws;
    size_t off = 0;
    auto alloc = [&](size_t bytes) { void* p = ws + off; off += (bytes + 255) & ~255ull; return p; };
    short* qkvb  = (short*)alloc((size_t)MROWS * E3 * 2);
    short* vtb   = (short*)alloc((size_t)BC * NH * VT2_PER_BH * 2);
    short* attnb = (short*)alloc((size_t)MROWS * DIM * 2);
    float* betab = (float*)alloc((size_t)BC * NH * NQ * 4);
    float* ctr   = (float*)alloc((size_t)BC * NQ * 2 * 4 + 1024);
    (void)ws_size; (void)in_sizes; (void)n_in; (void)out_size;

    beta_ctr_kernel<<<MROWS / 4, 256, 0, stream>>>(feat, bw, bb, bbox, betab, ctr);
    gemm_k256<true, true, false, true, true><<<dim3(E3 / 64, MROWS / 64), 256, 0, stream>>>(feat, in_w, in_b, qkvb, E3, vtb);
    attn_kernel<<<dim3((NQ + 31) / 32, BC * NH), 256, 0, stream>>>(qkvb, vtb, betab, ctr, attnb);
    gemm_k256<false, true, true, false, false><<<dim3(DIM / 64, MROWS / 64), 256, 0, stream>>>(attnb, out_w, out_b, out, DIM, nullptr);
}

// Round 13
// 59.793 us; speedup vs baseline: 1.2031x; 1.2031x over previous
//
#include <hip/hip_runtime.h>
#include <hip/hip_bf16.h>

#define BC 4
#define NQ 1200
#define DIM 256
#define NH 8
#define HD 32
#define E3 768
#define MROWS (BC*NQ)
#define SCALE 0.17677669529663687f
#define L2E 1.4426950408889634f
#define SL2E (SCALE * L2E)

// VT2 global layout: [b][h][hh(2)][chunk(160)][d16(16)][8 keys]
#define VT2_PER_BH 40960
#define VT2_PER_HH 20480

typedef __attribute__((ext_vector_type(8))) short bf16x8;
typedef __attribute__((ext_vector_type(4))) float f32x4;
typedef __attribute__((ext_vector_type(2))) unsigned u32x2;
typedef __attribute__((ext_vector_type(4))) unsigned u32x4;

#if __has_builtin(__builtin_amdgcn_permlane32_swap) && __has_builtin(__builtin_amdgcn_permlane16_swap)
#define HAVE_PERMLANE 1
#else
#define HAVE_PERMLANE 0
#endif

__device__ inline short f2bf(float f) {
    __hip_bfloat16 h = __float2bfloat16(f);
    return *reinterpret_cast<short*>(&h);
}
// HW packed f32->bf16 (RNE), 1 instr for 2 values (T12 recipe)
__device__ __forceinline__ unsigned cvtpk(float lo, float hi) {
    unsigned r;
    asm("v_cvt_pk_bf16_f32 %0, %1, %2" : "=v"(r) : "v"(lo), "v"(hi));
    return r;
}

// async global->LDS, 16B per lane; LDS dest = wave-uniform base + lane*16
__device__ __forceinline__ void gll16(const void* g, void* l) {
    __builtin_amdgcn_global_load_lds(
        (const __attribute__((address_space(1))) unsigned*)g,
        (__attribute__((address_space(3))) unsigned*)l, 16, 0, 0);
}

// ---------------- beta (f32 exact) + center packing ----------------
__global__ void beta_ctr_kernel(const float* __restrict__ feat, const float* __restrict__ bw,
                                const float* __restrict__ bb, const float* __restrict__ bbox,
                                float* __restrict__ beta, float* __restrict__ ctr) {
    int gw = (blockIdx.x * 256 + threadIdx.x) >> 6;   // one wave per (b,n)
    int lane = threadIdx.x & 63;
    if (gw >= MROWS) return;
    const float* frow = feat + (size_t)gw * DIM;
    float acc[NH];
#pragma unroll
    for (int h = 0; h < NH; ++h) acc[h] = 0.f;
#pragma unroll
    for (int it = 0; it < DIM / 64; ++it) {
        int d = it * 64 + lane;
        float f = frow[d];
#pragma unroll
        for (int h = 0; h < NH; ++h) acc[h] += f * bw[h * DIM + d];
    }
#pragma unroll
    for (int h = 0; h < NH; ++h) {
#pragma unroll
        for (int off = 32; off; off >>= 1) acc[h] += __shfl_xor(acc[h], off);
    }
    int b = gw / NQ, n = gw % NQ;
#pragma unroll
    for (int h = 0; h < NH; ++h) {
        float v = acc[h] + bb[h];
        if (lane == h) beta[(b * NH + h) * NQ + n] = v;
    }
    if (lane == 0) {
        ctr[gw * 2]     = bbox[(size_t)gw * 10];
        ctr[gw * 2 + 1] = bbox[(size_t)gw * 10 + 1];
    }
}

// ---------------- GEMM: C[M,E] = A[M,256] * W[E,256]^T + bias ----------------
template<bool AF32, bool BF32, bool OUTF32, bool VTOUT, bool QSCALE>
__global__ __launch_bounds__(256) void gemm_k256(const void* __restrict__ Av,
                                                 const void* __restrict__ Bv,
                                                 const float* __restrict__ bias,
                                                 void* __restrict__ Cout, int Edim,
                                                 short* __restrict__ vtout) {
    __shared__ short as[64][40];
    __shared__ short bs[64][40];
    int m0 = blockIdx.y * 64, e0 = blockIdx.x * 64;
    int t = threadIdx.x, lane = t & 63, wid = t >> 6;
    int wr = (wid >> 1) * 32, wc = (wid & 1) * 32;
    f32x4 acc[2][2] = {};
    int lrow = t >> 2, lch = t & 3;
    const float qs = (QSCALE && e0 < DIM) ? SL2E : 1.f;

    for (int ks = 0; ks < DIM / 32; ++ks) {
        bf16x8 av, wv;
        if (AF32) {
            const float* A = (const float*)Av;
            float4 f0 = *(const float4*)(A + (size_t)(m0 + lrow) * DIM + ks * 32 + lch * 8);
            float4 f1 = *(const float4*)(A + (size_t)(m0 + lrow) * DIM + ks * 32 + lch * 8 + 4);
            u32x4 p = {cvtpk(f0.x, f0.y), cvtpk(f0.z, f0.w),
                       cvtpk(f1.x, f1.y), cvtpk(f1.z, f1.w)};
            av = __builtin_bit_cast(bf16x8, p);
        } else {
            av = *(const bf16x8*)((const short*)Av + (size_t)(m0 + lrow) * DIM + ks * 32 + lch * 8);
        }
        if (BF32) {
            const float* B = (const float*)Bv;
            float4 f0 = *(const float4*)(B + (size_t)(e0 + lrow) * DIM + ks * 32 + lch * 8);
            float4 f1 = *(const float4*)(B + (size_t)(e0 + lrow) * DIM + ks * 32 + lch * 8 + 4);
            u32x4 p = {cvtpk(f0.x * qs, f0.y * qs), cvtpk(f0.z * qs, f0.w * qs),
                       cvtpk(f1.x * qs, f1.y * qs), cvtpk(f1.z * qs, f1.w * qs)};
            wv = __builtin_bit_cast(bf16x8, p);
        } else {
            wv = *(const bf16x8*)((const short*)Bv + (size_t)(e0 + lrow) * DIM + ks * 32 + lch * 8);
        }
        __syncthreads();
        *(bf16x8*)&as[lrow][lch * 8] = av;
        *(bf16x8*)&bs[lrow][lch * 8] = wv;
        __syncthreads();
#pragma unroll
        for (int sm = 0; sm < 2; ++sm) {
            bf16x8 af = *(const bf16x8*)&as[wr + sm * 16 + (lane & 15)][(lane >> 4) * 8];
#pragma unroll
            for (int sn = 0; sn < 2; ++sn) {
                bf16x8 bfv = *(const bf16x8*)&bs[wc + sn * 16 + (lane & 15)][(lane >> 4) * 8];
                acc[sm][sn] = __builtin_amdgcn_mfma_f32_16x16x32_bf16(af, bfv, acc[sm][sn], 0, 0, 0);
            }
        }
    }
#pragma unroll
    for (int sm = 0; sm < 2; ++sm)
#pragma unroll
        for (int sn = 0; sn < 2; ++sn) {
            int e = e0 + wc + sn * 16 + (lane & 15);
            float bv = bias[e];
            if (QSCALE && e < DIM) bv *= SL2E;
            float vals[4];
            int mbase = m0 + wr + sm * 16 + (lane >> 4) * 4;
#pragma unroll
            for (int r = 0; r < 4; ++r) vals[r] = acc[sm][sn][r] + bv;
            if (VTOUT && e >= 2 * DIM) {
                int dv = e - 2 * DIM;
                int hv = dv >> 5, dd = dv & 31;
                int hh = dd >> 4, di = dd & 15;
                int bb = mbase / NQ, nn = mbase - bb * NQ;   // 4-key group never crosses b
                u32x2 o = {cvtpk(vals[0], vals[1]), cvtpk(vals[2], vals[3])};
                size_t off = (size_t)(bb * NH + hv) * VT2_PER_BH + hh * VT2_PER_HH
                           + (nn >> 3) * 128 + di * 8 + (nn & 7);
                *(u32x2*)&vtout[off] = o;
            } else {
#pragma unroll
                for (int r = 0; r < 4; ++r) {
                    int m = mbase + r;
                    if (OUTF32) ((float*)Cout)[(size_t)m * Edim + e] = vals[r];
                    else        ((short*)Cout)[(size_t)m * Edim + e] = f2bf(vals[r]);
                }
            }
        }
}

// ---------------- fused flash attention ----------------
// grid: (38, B*H); block 256 = 4 waves = 2 qgroup x 2 ksplit; wave-tile 16q x 64k.
// gll16 double-buffered K/V/CK LDS staging (one barrier/tile), shuffle-free
// common path, P redistributed IN-REGISTER via permlane builtins (verified R12).
#define KT_OFF 0
#define VT_OFF 8192
#define CK_OFF 16384
#define BUFSZ 17408
#if HAVE_PERMLANE
#define SMEM_SZ (2*BUFSZ)
#else
#define PL_OFF (2*BUFSZ)
#define SMEM_SZ (2*BUFSZ + 4096)
#endif
__global__ __launch_bounds__(256, 4) void attn_kernel(const short* __restrict__ qkv,
                                                      const short* __restrict__ vt2,
                                                      const float* __restrict__ beta,
                                                      const float* __restrict__ ctr,
                                                      short* __restrict__ attnb) {
    __shared__ __align__(16) char smem[SMEM_SZ];

    const int t = threadIdx.x, lane = t & 63, w = t >> 6;
    const int g = lane >> 4, i = lane & 15;
    const int qg = w >> 1, ksp = w & 1;
    const int bh = blockIdx.y, b = bh >> 3, h = bh & 7;
    const int q0 = blockIdx.x * 32 + qg * 16;
    const int q = q0 + i, qc = min(q, NQ - 1);
    const int kwb = ksp * 64;
    const int bq = b * NQ;

    bf16x8 qf = *(const bf16x8*)(qkv + (size_t)(bq + qc) * E3 + h * HD + g * 8);  // pre-scaled
    const float cqx = ctr[(bq + qc) * 2];
    const float cqy = ctr[(bq + qc) * 2 + 1];
    const float nbql = -beta[(b * NH + h) * NQ + qc] * L2E;

    const short onebf = (short)0x3F80;
    const bf16x8 ones = {onebf, onebf, onebf, onebf, onebf, onebf, onebf, onebf};

    float mcur = 0.f;
    f32x4 o0 = {}, o1 = {}, oS = {};              // oS: lsum via ones-row MFMA

    // staging source pointers (advance per tile; OOB lands in owned ws, masked)
    const int koff = ((t >> 6) << 4) + (t & 15);
    const short* kld0 = qkv + (size_t)bq * E3 + DIM + h * HD + (size_t)koff * E3 + ((t >> 4) & 3) * 8;
    const short* kld1 = kld0 + (size_t)64 * E3;
    const short* vld0 = vt2 + (size_t)bh * VT2_PER_BH + (((t >> 4) & 15)) * 128 + (t & 15) * 8;
    const short* vld1 = vld0 + VT2_PER_HH;
    const char*  cld  = (const char*)(ctr + (size_t)bq * 2) + lane * 16;

    auto stage_issue = [&](int base) {
        gll16(kld0, &smem[base + KT_OFF + t * 16]);
        gll16(kld1, &smem[base + KT_OFF + (t + 256) * 16]);
        gll16(vld0, &smem[base + VT_OFF + t * 16]);
        gll16(vld1, &smem[base + VT_OFF + (t + 256) * 16]);
        if (w == 0) gll16(cld, &smem[base + CK_OFF + lane * 16]);
        kld0 += (size_t)128 * E3; kld1 += (size_t)128 * E3;
        vld0 += 2048; vld1 += 2048; cld += 1024;
    };

    stage_issue(0);
    __syncthreads();              // implicit vmcnt(0): tile 0 resident
    int cur = 0;

    for (int kb = 0; kb < NQ; kb += 128) {
        const bool haveNext = (kb + 128 < NQ);
        const bool tail = (kb + 128 > NQ);
        if (haveNext) stage_issue((cur ^ 1) * BUFSZ);   // async; completes by next barrier

        const int cb = cur * BUFSZ;
        float st[16];
        f32x4 cinit = {-mcur, -mcur, -mcur, -mcur};     // bake -m into MFMA C
#pragma unroll
        for (int kcl = 0; kcl < 4; ++kcl) {
            bf16x8 af = *(const bf16x8*)&smem[cb + KT_OFF + (((ksp * 4 + kcl) * 64 + lane) << 4)];
            f32x4 s = __builtin_amdgcn_mfma_f32_16x16x32_bf16(af, qf, cinit, 0, 0, 0);
            int lk = kwb + kcl * 16 + 4 * g;
            float4 cA = *(const float4*)&smem[cb + CK_OFF + lk * 8];
            float4 cB = *(const float4*)&smem[cb + CK_OFF + lk * 8 + 16];
            float cxv[4] = {cA.x, cA.z, cB.x, cB.z};
            float cyv[4] = {cA.y, cA.w, cB.y, cB.w};
#pragma unroll
            for (int r = 0; r < 4; ++r) {
                float dx = cqx - cxv[r], dy = cqy - cyv[r];
                float d2 = __builtin_fmaf(dx, dx, dy * dy);
                float dist = __builtin_amdgcn_sqrtf(d2);
                st[kcl * 4 + r] = __builtin_fmaf(dist, nbql, s[r]);
            }
            if (tail) {
#pragma unroll
                for (int r = 0; r < 4; ++r)
                    if (kb + lk + r >= NQ) st[kcl * 4 + r] = -1e30f;
            }
        }

        // ---- local max only (no shuffles); rescale branch is rare & wave-uniform ----
        float a0 = fmaxf(fmaxf(st[0],  st[1]),  st[2]);
        float a1 = fmaxf(fmaxf(st[3],  st[4]),  st[5]);
        float a2 = fmaxf(fmaxf(st[6],  st[7]),  st[8]);
        float a3 = fmaxf(fmaxf(st[9],  st[10]), st[11]);
        float a4 = fmaxf(fmaxf(st[12], st[13]), st[14]);
        float vm = fmaxf(fmaxf(fmaxf(a0, a1), a2), fmaxf(fmaxf(a3, a4), st[15]));
        if (!__all(vm <= 8.0f)) {
            float vr = fmaxf(vm, __shfl_xor(vm, 16));   // row max (only when needed)
            vr = fmaxf(vr, __shfl_xor(vr, 32));
            float dm = fmaxf(vr, 0.f);
            float al = __builtin_amdgcn_exp2f(-dm);
            mcur += dm;
#pragma unroll
            for (int r = 0; r < 4; ++r) { o0[r] *= al; o1[r] *= al; }
            oS[0] *= al;                                 // only oS[0] is ever read
#pragma unroll
            for (int x = 0; x < 16; ++x) st[x] -= dm;
        }
#pragma unroll
        for (int x = 0; x < 16; ++x) st[x] = __builtin_amdgcn_exp2f(st[x]);

        // ---- P -> bf16 words ----
        unsigned pk0[4], pk1[4];
#pragma unroll
        for (int kcl = 0; kcl < 4; ++kcl) {
            pk0[kcl] = cvtpk(st[kcl * 4 + 0], st[kcl * 4 + 1]);
            pk1[kcl] = cvtpk(st[kcl * 4 + 2], st[kcl * 4 + 3]);
        }

        // ---- PV per 32-key chunk (in-register P redistribution, verified R12) ----
#pragma unroll
        for (int kc2 = 0; kc2 < 2; ++kc2) {
            bf16x8 pbf;
#if HAVE_PERMLANE
            u32x2 aa = __builtin_amdgcn_permlane32_swap(pk0[2 * kc2], pk0[2 * kc2 + 1], false, false);
            u32x2 bbp = __builtin_amdgcn_permlane16_swap(aa[0], aa[1], false, false);
            u32x2 cc = __builtin_amdgcn_permlane32_swap(pk1[2 * kc2], pk1[2 * kc2 + 1], false, false);
            u32x2 ddp = __builtin_amdgcn_permlane16_swap(cc[0], cc[1], false, false);
            u32x4 pv = {bbp[0], ddp[0], bbp[1], ddp[1]};
            pbf = __builtin_bit_cast(bf16x8, pv);
#else
#pragma unroll
            for (int kk = 0; kk < 2; ++kk) {
                int kcl = 2 * kc2 + kk;
                u32x2 pw = {pk0[kcl], pk1[kcl]};
                *(u32x2*)&smem[PL_OFF + (w << 10) + (((kk << 1) + (g >> 1)) << 8) + (i << 4) + ((g & 1) << 3)] = pw;
            }
            pbf = *(const bf16x8*)&smem[PL_OFF + (w << 10) + (g << 8) + (i << 4)];
#endif
            int vidx = (8 * ksp + 4 * kc2 + g) * 16 + i;
            bf16x8 vf0 = *(const bf16x8*)&smem[cb + VT_OFF + (vidx << 4)];
            bf16x8 vf1 = *(const bf16x8*)&smem[cb + VT_OFF + ((256 + vidx) << 4)];
            __builtin_amdgcn_s_setprio(1);
            o0 = __builtin_amdgcn_mfma_f32_16x16x32_bf16(vf0, pbf, o0, 0, 0, 0);
            o1 = __builtin_amdgcn_mfma_f32_16x16x32_bf16(vf1, pbf, o1, 0, 0, 0);
            oS = __builtin_amdgcn_mfma_f32_16x16x32_bf16(ones, pbf, oS, 0, 0, 0);  // lsum row
            __builtin_amdgcn_s_setprio(0);
        }

        __syncthreads();          // drains gll (vmcnt 0) + publishes buf^1
        cur ^= 1;
    }

    // ---- merge the two key-splits per q-group (oS[0] already row-reduced) ----
    float lsum = oS[0];
    float* mrg = (float*)smem;                 // [4][64][10]
    float* my = mrg + (w * 64 + lane) * 10;
    my[0] = mcur; my[1] = lsum;
#pragma unroll
    for (int r = 0; r < 4; ++r) { my[2 + r] = o0[r]; my[6 + r] = o1[r]; }
    __syncthreads();
    const float* pr = mrg + ((w ^ 1) * 64 + lane) * 10;
    float m2 = pr[0], l2 = pr[1];
    float mN = fmaxf(mcur, m2);
    float a1 = __builtin_amdgcn_exp2f(mcur - mN);
    float a2 = __builtin_amdgcn_exp2f(m2 - mN);
    float inv = 1.f / (lsum * a1 + l2 * a2);
    int hh = w & 1;                            // this wave writes d-half hh
    f32x4 mine = hh ? o1 : o0;
    if (q < NQ) {
        float vals[4];
#pragma unroll
        for (int r = 0; r < 4; ++r) vals[r] = (mine[r] * a1 + pr[2 + hh * 4 + r] * a2) * inv;
        u32x2 outv = {cvtpk(vals[0], vals[1]), cvtpk(vals[2], vals[3])};
        *(u32x2*)&attnb[(size_t)(bq + q) * DIM + h * HD + hh * 16 + 4 * g] = outv;
    }
}

extern "C" void kernel_launch(void* const* d_in, const int* in_sizes, int n_in,
                              void* d_out, int out_size, void* d_ws, size_t ws_size,
                              hipStream_t stream) {
    const float* bbox  = (const float*)d_in[0];
    const float* feat  = (const float*)d_in[1];
    const float* bw    = (const float*)d_in[2];
    const float* bb    = (const float*)d_in[3];
    const float* in_w  = (const float*)d_in[4];
    const float* in_b  = (const float*)d_in[5];
    const float* out_w = (const float*)d_in[6];
    const float* out_b = (const float*)d_in[7];
    float* out = (float*)d_out;

    char* ws = (char*)d_ws;
    size_t off = 0;
    auto alloc = [&](size_t bytes) { void* p = ws + off; off += (bytes + 255) & ~255ull; return p; };
    short* qkvb  = (short*)alloc((size_t)MROWS * E3 * 2);
    short* vtb   = (short*)alloc((size_t)BC * NH * VT2_PER_BH * 2);
    short* attnb = (short*)alloc((size_t)MROWS * DIM * 2);
    float* betab = (float*)alloc((size_t)BC * NH * NQ * 4);
    float* ctr   = (float*)alloc((size_t)BC * NQ * 2 * 4 + 1024);
    (void)ws_size; (void)in_sizes; (void)n_in; (void)out_size;

    beta_ctr_kernel<<<MROWS / 4, 256, 0, stream>>>(feat, bw, bb, bbox, betab, ctr);
    gemm_k256<true, true, false, true, true><<<dim3(E3 / 64, MROWS / 64), 256, 0, stream>>>(feat, in_w, in_b, qkvb, E3, vtb);
    attn_kernel<<<dim3((NQ + 31) / 32, BC * NH), 256, 0, stream>>>(qkvb, vtb, betab, ctr, attnb);
    gemm_k256<false, true, true, false, false><<<dim3(DIM / 64, MROWS / 64), 256, 0, stream>>>(attnb, out_w, out_b, out, DIM, nullptr);
}

// Round 14
// 56.589 us; speedup vs baseline: 1.2712x; 1.0566x over previous
//
#include <hip/hip_runtime.h>
#include <hip/hip_bf16.h>

#define BC 4
#define NQ 1200
#define DIM 256
#define NH 8
#define HD 32
#define E3 768
#define MROWS (BC*NQ)
#define SCALE 0.17677669529663687f
#define L2E 1.4426950408889634f
#define SL2E (SCALE * L2E)

// VT2 global layout: [b][h][hh(2)][chunk(160)][d16(16)][8 keys]
#define VT2_PER_BH 40960
#define VT2_PER_HH 20480

typedef __attribute__((ext_vector_type(8))) short bf16x8;
typedef __attribute__((ext_vector_type(4))) float f32x4;
typedef __attribute__((ext_vector_type(2))) unsigned u32x2;
typedef __attribute__((ext_vector_type(4))) unsigned u32x4;

#if __has_builtin(__builtin_amdgcn_permlane32_swap) && __has_builtin(__builtin_amdgcn_permlane16_swap)
#define HAVE_PERMLANE 1
#else
#define HAVE_PERMLANE 0
#endif

__device__ inline short f2bf(float f) {
    __hip_bfloat16 h = __float2bfloat16(f);
    return *reinterpret_cast<short*>(&h);
}
// HW packed f32->bf16 (RNE), 1 instr for 2 values (T12 recipe)
__device__ __forceinline__ unsigned cvtpk(float lo, float hi) {
    unsigned r;
    asm("v_cvt_pk_bf16_f32 %0, %1, %2" : "=v"(r) : "v"(lo), "v"(hi));
    return r;
}

// async global->LDS, 16B per lane; LDS dest = wave-uniform base + lane*16
__device__ __forceinline__ void gll16(const void* g, void* l) {
    __builtin_amdgcn_global_load_lds(
        (const __attribute__((address_space(1))) unsigned*)g,
        (__attribute__((address_space(3))) unsigned*)l, 16, 0, 0);
}

// ---------------- prep: weight/feat bf16 conversion (ONCE) + beta + ctr ----------------
// grid 1928: [0,600) feat cvt | [600,696) in_w cvt (SL2E on Q rows) | [696,728) out_w | [728,1928) beta+ctr
__global__ __launch_bounds__(256) void prep_kernel(const float* __restrict__ feat,
                                                   const float* __restrict__ in_w,
                                                   const float* __restrict__ out_w,
                                                   const float* __restrict__ bw,
                                                   const float* __restrict__ bb,
                                                   const float* __restrict__ bbox,
                                                   short* __restrict__ featb,
                                                   short* __restrict__ wib,
                                                   short* __restrict__ wob,
                                                   float* __restrict__ beta,
                                                   float* __restrict__ ctr) {
    int bx = blockIdx.x;
    if (bx < 728) {
        const float* src; short* dst; int idx; float qs = 1.f;
        if (bx < 600)      { idx = bx * 256 + threadIdx.x;          src = feat;  dst = featb; }
        else if (bx < 696) { idx = (bx - 600) * 256 + threadIdx.x;  src = in_w;  dst = wib;
                             if ((idx >> 5) < DIM) qs = SL2E; }      // row = idx*8/256
        else               { idx = (bx - 696) * 256 + threadIdx.x;  src = out_w; dst = wob; }
        const float* s = src + (size_t)idx * 8;
        float4 f0 = *(const float4*)s, f1 = *(const float4*)(s + 4);
        u32x4 p = {cvtpk(f0.x * qs, f0.y * qs), cvtpk(f0.z * qs, f0.w * qs),
                   cvtpk(f1.x * qs, f1.y * qs), cvtpk(f1.z * qs, f1.w * qs)};
        *(u32x4*)(dst + (size_t)idx * 8) = p;
        return;
    }
    int gw = (bx - 728) * 4 + (threadIdx.x >> 6);   // one wave per (b,n)
    int lane = threadIdx.x & 63;
    const float* frow = feat + (size_t)gw * DIM;
    float acc[NH];
#pragma unroll
    for (int h = 0; h < NH; ++h) acc[h] = 0.f;
#pragma unroll
    for (int it = 0; it < DIM / 64; ++it) {
        int d = it * 64 + lane;
        float f = frow[d];
#pragma unroll
        for (int h = 0; h < NH; ++h) acc[h] += f * bw[h * DIM + d];
    }
#pragma unroll
    for (int h = 0; h < NH; ++h) {
#pragma unroll
        for (int off = 32; off; off >>= 1) acc[h] += __shfl_xor(acc[h], off);
    }
    int b = gw / NQ, n = gw % NQ;
#pragma unroll
    for (int h = 0; h < NH; ++h) {
        float v = acc[h] + bb[h];
        if (lane == h) beta[(b * NH + h) * NQ + n] = v;
    }
    if (lane == 0) {
        ctr[gw * 2]     = bbox[(size_t)gw * 10];
        ctr[gw * 2 + 1] = bbox[(size_t)gw * 10 + 1];
    }
}

// ---------------- GEMM (all-bf16): C[M,E] = A[M,256] * W[E,256]^T + bias ----------------
template<bool OUTF32, bool VTOUT, bool QSCALE_BIAS>
__global__ __launch_bounds__(256) void gemm_k256(const short* __restrict__ A,
                                                 const short* __restrict__ B,
                                                 const float* __restrict__ bias,
                                                 void* __restrict__ Cout, int Edim,
                                                 short* __restrict__ vtout) {
    __shared__ short as[64][40];
    __shared__ short bs[64][40];
    int m0 = blockIdx.y * 64, e0 = blockIdx.x * 64;
    int t = threadIdx.x, lane = t & 63, wid = t >> 6;
    int wr = (wid >> 1) * 32, wc = (wid & 1) * 32;
    f32x4 acc[2][2] = {};
    int lrow = t >> 2, lch = t & 3;

    for (int ks = 0; ks < DIM / 32; ++ks) {
        bf16x8 av = *(const bf16x8*)(A + (size_t)(m0 + lrow) * DIM + ks * 32 + lch * 8);
        bf16x8 wv = *(const bf16x8*)(B + (size_t)(e0 + lrow) * DIM + ks * 32 + lch * 8);
        __syncthreads();
        *(bf16x8*)&as[lrow][lch * 8] = av;
        *(bf16x8*)&bs[lrow][lch * 8] = wv;
        __syncthreads();
#pragma unroll
        for (int sm = 0; sm < 2; ++sm) {
            bf16x8 af = *(const bf16x8*)&as[wr + sm * 16 + (lane & 15)][(lane >> 4) * 8];
#pragma unroll
            for (int sn = 0; sn < 2; ++sn) {
                bf16x8 bfv = *(const bf16x8*)&bs[wc + sn * 16 + (lane & 15)][(lane >> 4) * 8];
                acc[sm][sn] = __builtin_amdgcn_mfma_f32_16x16x32_bf16(af, bfv, acc[sm][sn], 0, 0, 0);
            }
        }
    }
#pragma unroll
    for (int sm = 0; sm < 2; ++sm)
#pragma unroll
        for (int sn = 0; sn < 2; ++sn) {
            int e = e0 + wc + sn * 16 + (lane & 15);
            float bv = bias[e];
            if (QSCALE_BIAS && e < DIM) bv *= SL2E;
            float vals[4];
            int mbase = m0 + wr + sm * 16 + (lane >> 4) * 4;
#pragma unroll
            for (int r = 0; r < 4; ++r) vals[r] = acc[sm][sn][r] + bv;
            if (VTOUT && e >= 2 * DIM) {
                int dv = e - 2 * DIM;
                int hv = dv >> 5, dd = dv & 31;
                int hh = dd >> 4, di = dd & 15;
                int bb = mbase / NQ, nn = mbase - bb * NQ;   // 4-key group never crosses b
                u32x2 o = {cvtpk(vals[0], vals[1]), cvtpk(vals[2], vals[3])};
                size_t off = (size_t)(bb * NH + hv) * VT2_PER_BH + hh * VT2_PER_HH
                           + (nn >> 3) * 128 + di * 8 + (nn & 7);
                *(u32x2*)&vtout[off] = o;
            } else {
#pragma unroll
                for (int r = 0; r < 4; ++r) {
                    int m = mbase + r;
                    if (OUTF32) ((float*)Cout)[(size_t)m * Edim + e] = vals[r];
                    else        ((short*)Cout)[(size_t)m * Edim + e] = f2bf(vals[r]);
                }
            }
        }
}

// ---------------- fused flash attention (unchanged from R13) ----------------
#define KT_OFF 0
#define VT_OFF 8192
#define CK_OFF 16384
#define BUFSZ 17408
#if HAVE_PERMLANE
#define SMEM_SZ (2*BUFSZ)
#else
#define PL_OFF (2*BUFSZ)
#define SMEM_SZ (2*BUFSZ + 4096)
#endif
__global__ __launch_bounds__(256, 4) void attn_kernel(const short* __restrict__ qkv,
                                                      const short* __restrict__ vt2,
                                                      const float* __restrict__ beta,
                                                      const float* __restrict__ ctr,
                                                      short* __restrict__ attnb) {
    __shared__ __align__(16) char smem[SMEM_SZ];

    const int t = threadIdx.x, lane = t & 63, w = t >> 6;
    const int g = lane >> 4, i = lane & 15;
    const int qg = w >> 1, ksp = w & 1;
    const int bh = blockIdx.y, b = bh >> 3, h = bh & 7;
    const int q0 = blockIdx.x * 32 + qg * 16;
    const int q = q0 + i, qc = min(q, NQ - 1);
    const int kwb = ksp * 64;
    const int bq = b * NQ;

    bf16x8 qf = *(const bf16x8*)(qkv + (size_t)(bq + qc) * E3 + h * HD + g * 8);  // pre-scaled
    const float cqx = ctr[(bq + qc) * 2];
    const float cqy = ctr[(bq + qc) * 2 + 1];
    const float nbql = -beta[(b * NH + h) * NQ + qc] * L2E;

    const short onebf = (short)0x3F80;
    const bf16x8 ones = {onebf, onebf, onebf, onebf, onebf, onebf, onebf, onebf};

    float mcur = 0.f;
    f32x4 o0 = {}, o1 = {}, oS = {};              // oS: lsum via ones-row MFMA

    // staging source pointers (advance per tile; OOB lands in owned ws, masked)
    const int koff = ((t >> 6) << 4) + (t & 15);
    const short* kld0 = qkv + (size_t)bq * E3 + DIM + h * HD + (size_t)koff * E3 + ((t >> 4) & 3) * 8;
    const short* kld1 = kld0 + (size_t)64 * E3;
    const short* vld0 = vt2 + (size_t)bh * VT2_PER_BH + (((t >> 4) & 15)) * 128 + (t & 15) * 8;
    const short* vld1 = vld0 + VT2_PER_HH;
    const char*  cld  = (const char*)(ctr + (size_t)bq * 2) + lane * 16;

    auto stage_issue = [&](int base) {
        gll16(kld0, &smem[base + KT_OFF + t * 16]);
        gll16(kld1, &smem[base + KT_OFF + (t + 256) * 16]);
        gll16(vld0, &smem[base + VT_OFF + t * 16]);
        gll16(vld1, &smem[base + VT_OFF + (t + 256) * 16]);
        if (w == 0) gll16(cld, &smem[base + CK_OFF + lane * 16]);
        kld0 += (size_t)128 * E3; kld1 += (size_t)128 * E3;
        vld0 += 2048; vld1 += 2048; cld += 1024;
    };

    stage_issue(0);
    __syncthreads();              // implicit vmcnt(0): tile 0 resident
    int cur = 0;

    for (int kb = 0; kb < NQ; kb += 128) {
        const bool haveNext = (kb + 128 < NQ);
        const bool tail = (kb + 128 > NQ);
        if (haveNext) stage_issue((cur ^ 1) * BUFSZ);   // async; completes by next barrier

        const int cb = cur * BUFSZ;
        float st[16];
        f32x4 cinit = {-mcur, -mcur, -mcur, -mcur};     // bake -m into MFMA C
#pragma unroll
        for (int kcl = 0; kcl < 4; ++kcl) {
            bf16x8 af = *(const bf16x8*)&smem[cb + KT_OFF + (((ksp * 4 + kcl) * 64 + lane) << 4)];
            f32x4 s = __builtin_amdgcn_mfma_f32_16x16x32_bf16(af, qf, cinit, 0, 0, 0);
            int lk = kwb + kcl * 16 + 4 * g;
            float4 cA = *(const float4*)&smem[cb + CK_OFF + lk * 8];
            float4 cB = *(const float4*)&smem[cb + CK_OFF + lk * 8 + 16];
            float cxv[4] = {cA.x, cA.z, cB.x, cB.z};
            float cyv[4] = {cA.y, cA.w, cB.y, cB.w};
#pragma unroll
            for (int r = 0; r < 4; ++r) {
                float dx = cqx - cxv[r], dy = cqy - cyv[r];
                float d2 = __builtin_fmaf(dx, dx, dy * dy);
                float dist = __builtin_amdgcn_sqrtf(d2);
                st[kcl * 4 + r] = __builtin_fmaf(dist, nbql, s[r]);
            }
            if (tail) {
#pragma unroll
                for (int r = 0; r < 4; ++r)
                    if (kb + lk + r >= NQ) st[kcl * 4 + r] = -1e30f;
            }
        }

        // ---- local max only (no shuffles); rescale branch is rare & wave-uniform ----
        float a0 = fmaxf(fmaxf(st[0],  st[1]),  st[2]);
        float a1 = fmaxf(fmaxf(st[3],  st[4]),  st[5]);
        float a2 = fmaxf(fmaxf(st[6],  st[7]),  st[8]);
        float a3 = fmaxf(fmaxf(st[9],  st[10]), st[11]);
        float a4 = fmaxf(fmaxf(st[12], st[13]), st[14]);
        float vm = fmaxf(fmaxf(fmaxf(a0, a1), a2), fmaxf(fmaxf(a3, a4), st[15]));
        if (!__all(vm <= 8.0f)) {
            float vr = fmaxf(vm, __shfl_xor(vm, 16));   // row max (only when needed)
            vr = fmaxf(vr, __shfl_xor(vr, 32));
            float dm = fmaxf(vr, 0.f);
            float al = __builtin_amdgcn_exp2f(-dm);
            mcur += dm;
#pragma unroll
            for (int r = 0; r < 4; ++r) { o0[r] *= al; o1[r] *= al; }
            oS[0] *= al;                                 // only oS[0] is ever read
#pragma unroll
            for (int x = 0; x < 16; ++x) st[x] -= dm;
        }
#pragma unroll
        for (int x = 0; x < 16; ++x) st[x] = __builtin_amdgcn_exp2f(st[x]);

        // ---- P -> bf16 words ----
        unsigned pk0[4], pk1[4];
#pragma unroll
        for (int kcl = 0; kcl < 4; ++kcl) {
            pk0[kcl] = cvtpk(st[kcl * 4 + 0], st[kcl * 4 + 1]);
            pk1[kcl] = cvtpk(st[kcl * 4 + 2], st[kcl * 4 + 3]);
        }

        // ---- PV per 32-key chunk (in-register P redistribution, verified R12) ----
#pragma unroll
        for (int kc2 = 0; kc2 < 2; ++kc2) {
            bf16x8 pbf;
#if HAVE_PERMLANE
            u32x2 aa = __builtin_amdgcn_permlane32_swap(pk0[2 * kc2], pk0[2 * kc2 + 1], false, false);
            u32x2 bbp = __builtin_amdgcn_permlane16_swap(aa[0], aa[1], false, false);
            u32x2 cc = __builtin_amdgcn_permlane32_swap(pk1[2 * kc2], pk1[2 * kc2 + 1], false, false);
            u32x2 ddp = __builtin_amdgcn_permlane16_swap(cc[0], cc[1], false, false);
            u32x4 pv = {bbp[0], ddp[0], bbp[1], ddp[1]};
            pbf = __builtin_bit_cast(bf16x8, pv);
#else
#pragma unroll
            for (int kk = 0; kk < 2; ++kk) {
                int kcl = 2 * kc2 + kk;
                u32x2 pw = {pk0[kcl], pk1[kcl]};
                *(u32x2*)&smem[PL_OFF + (w << 10) + (((kk << 1) + (g >> 1)) << 8) + (i << 4) + ((g & 1) << 3)] = pw;
            }
            pbf = *(const bf16x8*)&smem[PL_OFF + (w << 10) + (g << 8) + (i << 4)];
#endif
            int vidx = (8 * ksp + 4 * kc2 + g) * 16 + i;
            bf16x8 vf0 = *(const bf16x8*)&smem[cb + VT_OFF + (vidx << 4)];
            bf16x8 vf1 = *(const bf16x8*)&smem[cb + VT_OFF + ((256 + vidx) << 4)];
            __builtin_amdgcn_s_setprio(1);
            o0 = __builtin_amdgcn_mfma_f32_16x16x32_bf16(vf0, pbf, o0, 0, 0, 0);
            o1 = __builtin_amdgcn_mfma_f32_16x16x32_bf16(vf1, pbf, o1, 0, 0, 0);
            oS = __builtin_amdgcn_mfma_f32_16x16x32_bf16(ones, pbf, oS, 0, 0, 0);  // lsum row
            __builtin_amdgcn_s_setprio(0);
        }

        __syncthreads();          // drains gll (vmcnt 0) + publishes buf^1
        cur ^= 1;
    }

    // ---- merge the two key-splits per q-group (oS[0] already row-reduced) ----
    float lsum = oS[0];
    float* mrg = (float*)smem;                 // [4][64][10]
    float* my = mrg + (w * 64 + lane) * 10;
    my[0] = mcur; my[1] = lsum;
#pragma unroll
    for (int r = 0; r < 4; ++r) { my[2 + r] = o0[r]; my[6 + r] = o1[r]; }
    __syncthreads();
    const float* pr = mrg + ((w ^ 1) * 64 + lane) * 10;
    float m2 = pr[0], l2 = pr[1];
    float mN = fmaxf(mcur, m2);
    float a1 = __builtin_amdgcn_exp2f(mcur - mN);
    float a2 = __builtin_amdgcn_exp2f(m2 - mN);
    float inv = 1.f / (lsum * a1 + l2 * a2);
    int hh = w & 1;                            // this wave writes d-half hh
    f32x4 mine = hh ? o1 : o0;
    if (q < NQ) {
        float vals[4];
#pragma unroll
        for (int r = 0; r < 4; ++r) vals[r] = (mine[r] * a1 + pr[2 + hh * 4 + r] * a2) * inv;
        u32x2 outv = {cvtpk(vals[0], vals[1]), cvtpk(vals[2], vals[3])};
        *(u32x2*)&attnb[(size_t)(bq + q) * DIM + h * HD + hh * 16 + 4 * g] = outv;
    }
}

extern "C" void kernel_launch(void* const* d_in, const int* in_sizes, int n_in,
                              void* d_out, int out_size, void* d_ws, size_t ws_size,
                              hipStream_t stream) {
    const float* bbox  = (const float*)d_in[0];
    const float* feat  = (const float*)d_in[1];
    const float* bw    = (const float*)d_in[2];
    const float* bb    = (const float*)d_in[3];
    const float* in_w  = (const float*)d_in[4];
    const float* in_b  = (const float*)d_in[5];
    const float* out_w = (const float*)d_in[6];
    const float* out_b = (const float*)d_in[7];
    float* out = (float*)d_out;

    char* ws = (char*)d_ws;
    size_t off = 0;
    auto alloc = [&](size_t bytes) { void* p = ws + off; off += (bytes + 255) & ~255ull; return p; };
    short* qkvb  = (short*)alloc((size_t)MROWS * E3 * 2);
    short* vtb   = (short*)alloc((size_t)BC * NH * VT2_PER_BH * 2);
    short* attnb = (short*)alloc((size_t)MROWS * DIM * 2);
    short* featb = (short*)alloc((size_t)MROWS * DIM * 2);
    short* wib   = (short*)alloc((size_t)E3 * DIM * 2);
    short* wob   = (short*)alloc((size_t)DIM * DIM * 2);
    float* betab = (float*)alloc((size_t)BC * NH * NQ * 4);
    float* ctr   = (float*)alloc((size_t)BC * NQ * 2 * 4 + 1024);
    (void)ws_size; (void)in_sizes; (void)n_in; (void)out_size;

    prep_kernel<<<1928, 256, 0, stream>>>(feat, in_w, out_w, bw, bb, bbox, featb, wib, wob, betab, ctr);
    gemm_k256<false, true, true><<<dim3(E3 / 64, MROWS / 64), 256, 0, stream>>>(featb, wib, in_b, qkvb, E3, vtb);
    attn_kernel<<<dim3((NQ + 31) / 32, BC * NH), 256, 0, stream>>>(qkvb, vtb, betab, ctr, attnb);
    gemm_k256<true, false, false><<<dim3(DIM / 64, MROWS / 64), 256, 0, stream>>>(attnb, wob, out_b, out, DIM, nullptr);
}

// Round 15
// 55.739 us; speedup vs baseline: 1.2906x; 1.0152x over previous
//
#include <hip/hip_runtime.h>
#include <hip/hip_bf16.h>

#define BC 4
#define NQ 1200
#define DIM 256
#define NH 8
#define HD 32
#define E3 768
#define MROWS (BC*NQ)
#define SCALE 0.17677669529663687f
#define L2E 1.4426950408889634f
#define SL2E (SCALE * L2E)

// VT2 global layout: [b][h][hh(2)][chunk(160)][d16(16)][8 keys]
#define VT2_PER_BH 40960
#define VT2_PER_HH 20480

typedef __attribute__((ext_vector_type(8))) short bf16x8;
typedef __attribute__((ext_vector_type(4))) float f32x4;
typedef __attribute__((ext_vector_type(2))) unsigned u32x2;
typedef __attribute__((ext_vector_type(4))) unsigned u32x4;

#if __has_builtin(__builtin_amdgcn_permlane32_swap) && __has_builtin(__builtin_amdgcn_permlane16_swap)
#define HAVE_PERMLANE 1
#else
#define HAVE_PERMLANE 0
#endif

__device__ inline short f2bf(float f) {
    __hip_bfloat16 h = __float2bfloat16(f);
    return *reinterpret_cast<short*>(&h);
}
// HW packed f32->bf16 (RNE), 1 instr for 2 values (T12 recipe)
__device__ __forceinline__ unsigned cvtpk(float lo, float hi) {
    unsigned r;
    asm("v_cvt_pk_bf16_f32 %0, %1, %2" : "=v"(r) : "v"(lo), "v"(hi));
    return r;
}

// async global->LDS, 16B per lane; LDS dest = wave-uniform base + lane*16
__device__ __forceinline__ void gll16(const void* g, void* l) {
    __builtin_amdgcn_global_load_lds(
        (const __attribute__((address_space(1))) unsigned*)g,
        (__attribute__((address_space(3))) unsigned*)l, 16, 0, 0);
}

// ---------------- prep: weight/feat bf16 conversion (ONCE) + beta + ctr ----------------
// grid 1928: [0,600) feat cvt | [600,696) in_w cvt (SL2E on Q rows) | [696,728) out_w | [728,1928) beta+ctr
__global__ __launch_bounds__(256) void prep_kernel(const float* __restrict__ feat,
                                                   const float* __restrict__ in_w,
                                                   const float* __restrict__ out_w,
                                                   const float* __restrict__ bw,
                                                   const float* __restrict__ bb,
                                                   const float* __restrict__ bbox,
                                                   short* __restrict__ featb,
                                                   short* __restrict__ wib,
                                                   short* __restrict__ wob,
                                                   float* __restrict__ beta,
                                                   float* __restrict__ ctr) {
    int bx = blockIdx.x;
    if (bx < 728) {
        const float* src; short* dst; int idx; float qs = 1.f;
        if (bx < 600)      { idx = bx * 256 + threadIdx.x;          src = feat;  dst = featb; }
        else if (bx < 696) { idx = (bx - 600) * 256 + threadIdx.x;  src = in_w;  dst = wib;
                             if ((idx >> 5) < DIM) qs = SL2E; }      // row = idx*8/256
        else               { idx = (bx - 696) * 256 + threadIdx.x;  src = out_w; dst = wob; }
        const float* s = src + (size_t)idx * 8;
        float4 f0 = *(const float4*)s, f1 = *(const float4*)(s + 4);
        u32x4 p = {cvtpk(f0.x * qs, f0.y * qs), cvtpk(f0.z * qs, f0.w * qs),
                   cvtpk(f1.x * qs, f1.y * qs), cvtpk(f1.z * qs, f1.w * qs)};
        *(u32x4*)(dst + (size_t)idx * 8) = p;
        return;
    }
    int gw = (bx - 728) * 4 + (threadIdx.x >> 6);   // one wave per (b,n)
    int lane = threadIdx.x & 63;
    const float* frow = feat + (size_t)gw * DIM;
    float acc[NH];
#pragma unroll
    for (int h = 0; h < NH; ++h) acc[h] = 0.f;
#pragma unroll
    for (int it = 0; it < DIM / 64; ++it) {
        int d = it * 64 + lane;
        float f = frow[d];
#pragma unroll
        for (int h = 0; h < NH; ++h) acc[h] += f * bw[h * DIM + d];
    }
#pragma unroll
    for (int h = 0; h < NH; ++h) {
#pragma unroll
        for (int off = 32; off; off >>= 1) acc[h] += __shfl_xor(acc[h], off);
    }
    int b = gw / NQ, n = gw % NQ;
#pragma unroll
    for (int h = 0; h < NH; ++h) {
        float v = acc[h] + bb[h];
        if (lane == h) beta[(b * NH + h) * NQ + n] = v;
    }
    if (lane == 0) {
        ctr[gw * 2]     = bbox[(size_t)gw * 10];
        ctr[gw * 2 + 1] = bbox[(size_t)gw * 10 + 1];
    }
}

// ---------------- GEMM (all-bf16): C[M,E] = A[M,256] * W[E,256]^T + bias ----------------
template<bool OUTF32, bool VTOUT, bool QSCALE_BIAS>
__global__ __launch_bounds__(256) void gemm_k256(const short* __restrict__ A,
                                                 const short* __restrict__ B,
                                                 const float* __restrict__ bias,
                                                 void* __restrict__ Cout, int Edim,
                                                 short* __restrict__ vtout) {
    __shared__ short as[64][40];
    __shared__ short bs[64][40];
    int m0 = blockIdx.y * 64, e0 = blockIdx.x * 64;
    int t = threadIdx.x, lane = t & 63, wid = t >> 6;
    int wr = (wid >> 1) * 32, wc = (wid & 1) * 32;
    f32x4 acc[2][2] = {};
    int lrow = t >> 2, lch = t & 3;

    for (int ks = 0; ks < DIM / 32; ++ks) {
        bf16x8 av = *(const bf16x8*)(A + (size_t)(m0 + lrow) * DIM + ks * 32 + lch * 8);
        bf16x8 wv = *(const bf16x8*)(B + (size_t)(e0 + lrow) * DIM + ks * 32 + lch * 8);
        __syncthreads();
        *(bf16x8*)&as[lrow][lch * 8] = av;
        *(bf16x8*)&bs[lrow][lch * 8] = wv;
        __syncthreads();
#pragma unroll
        for (int sm = 0; sm < 2; ++sm) {
            bf16x8 af = *(const bf16x8*)&as[wr + sm * 16 + (lane & 15)][(lane >> 4) * 8];
#pragma unroll
            for (int sn = 0; sn < 2; ++sn) {
                bf16x8 bfv = *(const bf16x8*)&bs[wc + sn * 16 + (lane & 15)][(lane >> 4) * 8];
                acc[sm][sn] = __builtin_amdgcn_mfma_f32_16x16x32_bf16(af, bfv, acc[sm][sn], 0, 0, 0);
            }
        }
    }
#pragma unroll
    for (int sm = 0; sm < 2; ++sm)
#pragma unroll
        for (int sn = 0; sn < 2; ++sn) {
            int e = e0 + wc + sn * 16 + (lane & 15);
            float bv = bias[e];
            if (QSCALE_BIAS && e < DIM) bv *= SL2E;
            float vals[4];
            int mbase = m0 + wr + sm * 16 + (lane >> 4) * 4;
#pragma unroll
            for (int r = 0; r < 4; ++r) vals[r] = acc[sm][sn][r] + bv;
            if (VTOUT && e >= 2 * DIM) {
                int dv = e - 2 * DIM;
                int hv = dv >> 5, dd = dv & 31;
                int hh = dd >> 4, di = dd & 15;
                int bb = mbase / NQ, nn = mbase - bb * NQ;   // 4-key group never crosses b
                u32x2 o = {cvtpk(vals[0], vals[1]), cvtpk(vals[2], vals[3])};
                size_t off = (size_t)(bb * NH + hv) * VT2_PER_BH + hh * VT2_PER_HH
                           + (nn >> 3) * 128 + di * 8 + (nn & 7);
                *(u32x2*)&vtout[off] = o;
            } else {
#pragma unroll
                for (int r = 0; r < 4; ++r) {
                    int m = mbase + r;
                    if (OUTF32) ((float*)Cout)[(size_t)m * Edim + e] = vals[r];
                    else        ((short*)Cout)[(size_t)m * Edim + e] = f2bf(vals[r]);
                }
            }
        }
}

// ---------------- fused flash attention ----------------
// grid: (19, B*H); block 512 = 8 waves = 4 qgroup x 2 ksplit; wave-tile 16q x 64k.
// 64 q-rows share each staged 128-key tile -> staging cost per pair HALVES vs R13.
// gll16 double-buffered K/V/CK (one barrier/tile), shuffle-free common path,
// in-register P redistribution via permlane builtins (verified R12).
#define KT_OFF 0
#define VT_OFF 8192
#define CK_OFF 16384
#define BUFSZ 17408
#if HAVE_PERMLANE
#define SMEM_SZ (2*BUFSZ)
#else
#define PL_OFF (2*BUFSZ)
#define SMEM_SZ (2*BUFSZ + 8192)
#endif
__global__ __launch_bounds__(512, 4) void attn_kernel(const short* __restrict__ qkv,
                                                      const short* __restrict__ vt2,
                                                      const float* __restrict__ beta,
                                                      const float* __restrict__ ctr,
                                                      short* __restrict__ attnb) {
    __shared__ __align__(16) char smem[SMEM_SZ];

    const int t = threadIdx.x, lane = t & 63, w = t >> 6;
    const int g = lane >> 4, i = lane & 15;
    const int qg = w >> 1, ksp = w & 1;
    const int bh = blockIdx.y, b = bh >> 3, h = bh & 7;
    const int q0 = blockIdx.x * 64 + qg * 16;
    const int q = q0 + i, qc = min(q, NQ - 1);
    const int kwb = ksp * 64;
    const int bq = b * NQ;

    bf16x8 qf = *(const bf16x8*)(qkv + (size_t)(bq + qc) * E3 + h * HD + g * 8);  // pre-scaled
    const float cqx = ctr[(bq + qc) * 2];
    const float cqy = ctr[(bq + qc) * 2 + 1];
    const float nbql = -beta[(b * NH + h) * NQ + qc] * L2E;

    const short onebf = (short)0x3F80;
    const bf16x8 ones = {onebf, onebf, onebf, onebf, onebf, onebf, onebf, onebf};

    float mcur = 0.f;
    f32x4 o0 = {}, o1 = {}, oS = {};              // oS: lsum via ones-row MFMA

    // staging source pointers (advance per tile; OOB lands in owned ws, masked)
    // 512 threads: K = 1 gll/thread (key=((t>>6)<<4)|(t&15), chan=(t>>4)&3), V = 1 gll/thread
    const short* kld = qkv + (size_t)bq * E3 + DIM + h * HD
                     + (size_t)(((t >> 6) << 4) + (t & 15)) * E3 + ((t >> 4) & 3) * 8;
    const short* vld = vt2 + (size_t)bh * VT2_PER_BH + (t >> 8) * VT2_PER_HH
                     + (((t >> 4) & 15)) * 128 + (t & 15) * 8;
    const char*  cld = (const char*)(ctr + (size_t)bq * 2) + lane * 16;

    auto stage_issue = [&](int base) {
        gll16(kld, &smem[base + KT_OFF + t * 16]);
        gll16(vld, &smem[base + VT_OFF + t * 16]);
        if (w == 0) gll16(cld, &smem[base + CK_OFF + lane * 16]);
        kld += (size_t)128 * E3;
        vld += 2048; cld += 1024;
    };

    stage_issue(0);
    __syncthreads();              // implicit vmcnt(0): tile 0 resident
    int cur = 0;

    for (int kb = 0; kb < NQ; kb += 128) {
        const bool haveNext = (kb + 128 < NQ);
        const bool tail = (kb + 128 > NQ);
        if (haveNext) stage_issue((cur ^ 1) * BUFSZ);   // async; completes by next barrier

        const int cb = cur * BUFSZ;
        float st[16];
        f32x4 cinit = {-mcur, -mcur, -mcur, -mcur};     // bake -m into MFMA C
#pragma unroll
        for (int kcl = 0; kcl < 4; ++kcl) {
            bf16x8 af = *(const bf16x8*)&smem[cb + KT_OFF + (((ksp * 4 + kcl) * 64 + lane) << 4)];
            f32x4 s = __builtin_amdgcn_mfma_f32_16x16x32_bf16(af, qf, cinit, 0, 0, 0);
            int lk = kwb + kcl * 16 + 4 * g;
            float4 cA = *(const float4*)&smem[cb + CK_OFF + lk * 8];
            float4 cB = *(const float4*)&smem[cb + CK_OFF + lk * 8 + 16];
            float cxv[4] = {cA.x, cA.z, cB.x, cB.z};
            float cyv[4] = {cA.y, cA.w, cB.y, cB.w};
#pragma unroll
            for (int r = 0; r < 4; ++r) {
                float dx = cqx - cxv[r], dy = cqy - cyv[r];
                float d2 = __builtin_fmaf(dx, dx, dy * dy);
                float dist = __builtin_amdgcn_sqrtf(d2);
                st[kcl * 4 + r] = __builtin_fmaf(dist, nbql, s[r]);
            }
            if (tail) {
#pragma unroll
                for (int r = 0; r < 4; ++r)
                    if (kb + lk + r >= NQ) st[kcl * 4 + r] = -1e30f;
            }
        }

        // ---- local max only (no shuffles); rescale branch is rare & wave-uniform ----
        float a0 = fmaxf(fmaxf(st[0],  st[1]),  st[2]);
        float a1 = fmaxf(fmaxf(st[3],  st[4]),  st[5]);
        float a2 = fmaxf(fmaxf(st[6],  st[7]),  st[8]);
        float a3 = fmaxf(fmaxf(st[9],  st[10]), st[11]);
        float a4 = fmaxf(fmaxf(st[12], st[13]), st[14]);
        float vm = fmaxf(fmaxf(fmaxf(a0, a1), a2), fmaxf(fmaxf(a3, a4), st[15]));
        if (!__all(vm <= 8.0f)) {
            float vr = fmaxf(vm, __shfl_xor(vm, 16));   // row max (only when needed)
            vr = fmaxf(vr, __shfl_xor(vr, 32));
            float dm = fmaxf(vr, 0.f);
            float al = __builtin_amdgcn_exp2f(-dm);
            mcur += dm;
#pragma unroll
            for (int r = 0; r < 4; ++r) { o0[r] *= al; o1[r] *= al; }
            oS[0] *= al;                                 // only oS[0] is ever read
#pragma unroll
            for (int x = 0; x < 16; ++x) st[x] -= dm;
        }
#pragma unroll
        for (int x = 0; x < 16; ++x) st[x] = __builtin_amdgcn_exp2f(st[x]);

        // ---- P -> bf16 words ----
        unsigned pk0[4], pk1[4];
#pragma unroll
        for (int kcl = 0; kcl < 4; ++kcl) {
            pk0[kcl] = cvtpk(st[kcl * 4 + 0], st[kcl * 4 + 1]);
            pk1[kcl] = cvtpk(st[kcl * 4 + 2], st[kcl * 4 + 3]);
        }

        // ---- PV per 32-key chunk (in-register P redistribution, verified R12) ----
#pragma unroll
        for (int kc2 = 0; kc2 < 2; ++kc2) {
            bf16x8 pbf;
#if HAVE_PERMLANE
            u32x2 aa = __builtin_amdgcn_permlane32_swap(pk0[2 * kc2], pk0[2 * kc2 + 1], false, false);
            u32x2 bbp = __builtin_amdgcn_permlane16_swap(aa[0], aa[1], false, false);
            u32x2 cc = __builtin_amdgcn_permlane32_swap(pk1[2 * kc2], pk1[2 * kc2 + 1], false, false);
            u32x2 ddp = __builtin_amdgcn_permlane16_swap(cc[0], cc[1], false, false);
            u32x4 pv = {bbp[0], ddp[0], bbp[1], ddp[1]};
            pbf = __builtin_bit_cast(bf16x8, pv);
#else
#pragma unroll
            for (int kk = 0; kk < 2; ++kk) {
                int kcl = 2 * kc2 + kk;
                u32x2 pw = {pk0[kcl], pk1[kcl]};
                *(u32x2*)&smem[PL_OFF + (w << 10) + (((kk << 1) + (g >> 1)) << 8) + (i << 4) + ((g & 1) << 3)] = pw;
            }
            pbf = *(const bf16x8*)&smem[PL_OFF + (w << 10) + (g << 8) + (i << 4)];
#endif
            int vidx = (8 * ksp + 4 * kc2 + g) * 16 + i;
            bf16x8 vf0 = *(const bf16x8*)&smem[cb + VT_OFF + (vidx << 4)];
            bf16x8 vf1 = *(const bf16x8*)&smem[cb + VT_OFF + ((256 + vidx) << 4)];
            __builtin_amdgcn_s_setprio(1);
            o0 = __builtin_amdgcn_mfma_f32_16x16x32_bf16(vf0, pbf, o0, 0, 0, 0);
            o1 = __builtin_amdgcn_mfma_f32_16x16x32_bf16(vf1, pbf, o1, 0, 0, 0);
            oS = __builtin_amdgcn_mfma_f32_16x16x32_bf16(ones, pbf, oS, 0, 0, 0);  // lsum row
            __builtin_amdgcn_s_setprio(0);
        }

        __syncthreads();          // drains gll (vmcnt 0) + publishes buf^1
        cur ^= 1;
    }

    // ---- merge the two key-splits per q-group (oS[0] already row-reduced) ----
    float lsum = oS[0];
    float* mrg = (float*)smem;                 // [8][64][10]
    float* my = mrg + (w * 64 + lane) * 10;
    my[0] = mcur; my[1] = lsum;
#pragma unroll
    for (int r = 0; r < 4; ++r) { my[2 + r] = o0[r]; my[6 + r] = o1[r]; }
    __syncthreads();
    const float* pr = mrg + ((w ^ 1) * 64 + lane) * 10;
    float m2 = pr[0], l2 = pr[1];
    float mN = fmaxf(mcur, m2);
    float a1 = __builtin_amdgcn_exp2f(mcur - mN);
    float a2 = __builtin_amdgcn_exp2f(m2 - mN);
    float inv = 1.f / (lsum * a1 + l2 * a2);
    int hh = w & 1;                            // this wave writes d-half hh
    f32x4 mine = hh ? o1 : o0;
    if (q < NQ) {
        float vals[4];
#pragma unroll
        for (int r = 0; r < 4; ++r) vals[r] = (mine[r] * a1 + pr[2 + hh * 4 + r] * a2) * inv;
        u32x2 outv = {cvtpk(vals[0], vals[1]), cvtpk(vals[2], vals[3])};
        *(u32x2*)&attnb[(size_t)(bq + q) * DIM + h * HD + hh * 16 + 4 * g] = outv;
    }
}

extern "C" void kernel_launch(void* const* d_in, const int* in_sizes, int n_in,
                              void* d_out, int out_size, void* d_ws, size_t ws_size,
                              hipStream_t stream) {
    const float* bbox  = (const float*)d_in[0];
    const float* feat  = (const float*)d_in[1];
    const float* bw    = (const float*)d_in[2];
    const float* bb    = (const float*)d_in[3];
    const float* in_w  = (const float*)d_in[4];
    const float* in_b  = (const float*)d_in[5];
    const float* out_w = (const float*)d_in[6];
    const float* out_b = (const float*)d_in[7];
    float* out = (float*)d_out;

    char* ws = (char*)d_ws;
    size_t off = 0;
    auto alloc = [&](size_t bytes) { void* p = ws + off; off += (bytes + 255) & ~255ull; return p; };
    short* qkvb  = (short*)alloc((size_t)MROWS * E3 * 2);
    short* vtb   = (short*)alloc((size_t)BC * NH * VT2_PER_BH * 2);
    short* attnb = (short*)alloc((size_t)MROWS * DIM * 2);
    short* featb = (short*)alloc((size_t)MROWS * DIM * 2);
    short* wib   = (short*)alloc((size_t)E3 * DIM * 2);
    short* wob   = (short*)alloc((size_t)DIM * DIM * 2);
    float* betab = (float*)alloc((size_t)BC * NH * NQ * 4);
    float* ctr   = (float*)alloc((size_t)BC * NQ * 2 * 4 + 1024);
    (void)ws_size; (void)in_sizes; (void)n_in; (void)out_size;

    prep_kernel<<<1928, 256, 0, stream>>>(feat, in_w, out_w, bw, bb, bbox, featb, wib, wob, betab, ctr);
    gemm_k256<false, true, true><<<dim3(E3 / 64, MROWS / 64), 256, 0, stream>>>(featb, wib, in_b, qkvb, E3, vtb);
    attn_kernel<<<dim3(19, BC * NH), 512, 0, stream>>>(qkvb, vtb, betab, ctr, attnb);
    gemm_k256<true, false, false><<<dim3(DIM / 64, MROWS / 64), 256, 0, stream>>>(attnb, wob, out_b, out, DIM, nullptr);
}